// Round 1
// baseline (792.111 us; speedup 1.0000x reference)
//
#include <hip/hip_runtime.h>
#include <stdint.h>

// Problem constants (Mistral-7B-ish attention block, B=1, S=2048)
#define HIDDEN 4096
#define SEQ    2048
#define NH     32
#define NKV    8
#define HD     128

typedef __attribute__((ext_vector_type(8))) short short8;
typedef __attribute__((ext_vector_type(4))) float float4v;
typedef __attribute__((ext_vector_type(4))) unsigned short ushort4v;
typedef unsigned short bf16_t;

__device__ __forceinline__ bf16_t f2bf(float f) {
  unsigned u = __builtin_bit_cast(unsigned, f);
  u += 0x7fff + ((u >> 16) & 1);   // RNE
  return (bf16_t)(u >> 16);
}
__device__ __forceinline__ float bf2f(bf16_t h) {
  unsigned u = ((unsigned)h) << 16;
  return __builtin_bit_cast(float, u);
}

__device__ __forceinline__ void gload_lds16(const void* g, void* l) {
  __builtin_amdgcn_global_load_lds(
      (const __attribute__((address_space(1))) unsigned int*)g,
      (__attribute__((address_space(3))) unsigned int*)l, 16, 0, 0);
}

// ---------------- fp32 -> bf16 conversion ----------------
__global__ __launch_bounds__(256) void cvt_f32_bf16(const float* __restrict__ src,
                                                    bf16_t* __restrict__ dst) {
  long i = ((long)blockIdx.x * 256 + threadIdx.x) * 4;
  float4v f = *(const float4v*)(src + i);
  ushort4v o;
  o.x = f2bf(f.x); o.y = f2bf(f.y); o.z = f2bf(f.z); o.w = f2bf(f.w);
  *(ushort4v*)(dst + i) = o;
}

// ---------------- RoPE (in place, bf16) ----------------
// x: [S][n_heads*128]. pair (j, j+64): a' = a*cos - b*sin ; b' = b*cos + a*sin
__global__ __launch_bounds__(256) void rope_kernel(bf16_t* __restrict__ x,
                                                   const int* __restrict__ pos,
                                                   int n_heads) {
  long tid = (long)blockIdx.x * 256 + threadIdx.x;
  int j = (int)(tid & 63);
  long sh = tid >> 6;                 // s*n_heads + h
  int s = (int)(sh / n_heads);
  bf16_t* row = x + sh * 128;
  // inv_freq = 10000^(-j/64) = 2^(-j*log2(10000)/64)
  float f = (float)pos[s] * exp2f((float)j * (-13.28771237954945f / 64.f));
  float sn, cs;
  __sincosf(f, &sn, &cs);
  float a = bf2f(row[j]), b = bf2f(row[j + 64]);
  row[j]      = f2bf(a * cs - b * sn);
  row[j + 64] = f2bf(b * cs + a * sn);
}

// ---------------- V transpose: [S][NKV*128] -> [NKV][128][S] ----------------
__global__ __launch_bounds__(256) void transpose_v(const bf16_t* __restrict__ v,
                                                   bf16_t* __restrict__ vt) {
  __shared__ __align__(16) bf16_t tile[64][72];
  int s0 = blockIdx.x * 64, c0 = blockIdx.y * 64;
  int t = threadIdx.x;
#pragma unroll
  for (int j = 0; j < 8; ++j) {
    int u = j * 256 + t;                 // 2048 2-elem units
    int sl = u >> 5, dl = (u & 31) * 2;
    unsigned val = *(const unsigned*)(v + (long)(s0 + sl) * (NKV * HD) + c0 + dl);
    tile[sl][dl] = (bf16_t)(val & 0xffff);
    tile[sl][dl + 1] = (bf16_t)(val >> 16);
  }
  __syncthreads();
  int kvh = c0 >> 7, dbase = c0 & 127;
#pragma unroll
  for (int j = 0; j < 8; ++j) {
    int u = j * 256 + t;
    int dl = u >> 5, sl = (u & 31) * 2;
    unsigned val = (unsigned)tile[sl][dl] | ((unsigned)tile[sl + 1][dl] << 16);
    *(unsigned*)(vt + (long)kvh * HD * SEQ + (long)(dbase + dl) * SEQ + s0 + sl) = val;
  }
}

// ---------------- bf16 GEMM: C[M][N] = A[M][K] * B[N][K]^T ----------------
// m97-style: 128x128 tile, 4 waves (2x2 of 64x64), BK=32, global_load_lds staging.
template <int OUTF32>
__global__ __launch_bounds__(256) void gemm_bt(const bf16_t* __restrict__ A,
                                               const bf16_t* __restrict__ B,
                                               void* __restrict__ Cp,
                                               int M, int N, int K) {
  __shared__ __align__(16) bf16_t As[128 * 32];
  __shared__ __align__(16) bf16_t Bs[128 * 32];
  const int tid = threadIdx.x;
  const int w = tid >> 6, lane = tid & 63;
  const int bm = blockIdx.y, bn = blockIdx.x;
  const int wr = (w >> 1) * 64, wc = (w & 1) * 64;
  float4v acc[4][4] = {};
  const bf16_t* gA = A + (long)bm * 128 * K;
  const bf16_t* gB = B + (long)bn * 128 * K;
  const int c0 = w * 2, c1 = w * 2 + 1;
  const int rsub = lane >> 2, csub = (lane & 3) * 8;
  const int lr = lane & 15, lk = (lane >> 4) * 8;

  for (int k0 = 0; k0 < K; k0 += 32) {
    gload_lds16(gA + (long)(c0 * 16 + rsub) * K + k0 + csub, &As[c0 * 512]);
    gload_lds16(gA + (long)(c1 * 16 + rsub) * K + k0 + csub, &As[c1 * 512]);
    gload_lds16(gB + (long)(c0 * 16 + rsub) * K + k0 + csub, &Bs[c0 * 512]);
    gload_lds16(gB + (long)(c1 * 16 + rsub) * K + k0 + csub, &Bs[c1 * 512]);
    asm volatile("s_waitcnt vmcnt(0)" ::: "memory");
    __syncthreads();
    short8 af[4], bfr[4];
#pragma unroll
    for (int i = 0; i < 4; ++i)
      af[i] = *(const short8*)&As[(wr + i * 16 + lr) * 32 + lk];
#pragma unroll
    for (int i = 0; i < 4; ++i)
      bfr[i] = *(const short8*)&Bs[(wc + i * 16 + lr) * 32 + lk];
#pragma unroll
    for (int mi = 0; mi < 4; ++mi)
#pragma unroll
      for (int ni = 0; ni < 4; ++ni)
        acc[mi][ni] = __builtin_amdgcn_mfma_f32_16x16x32_bf16(af[mi], bfr[ni], acc[mi][ni], 0, 0, 0);
    __syncthreads();
  }
  const int lq = (lane >> 4) * 4;
#pragma unroll
  for (int mi = 0; mi < 4; ++mi)
#pragma unroll
    for (int ni = 0; ni < 4; ++ni) {
      int row = bm * 128 + wr + mi * 16 + lq;
      int col = bn * 128 + wc + ni * 16 + lr;
#pragma unroll
      for (int r = 0; r < 4; ++r) {
        float vv = acc[mi][ni][r];
        if (OUTF32)
          ((float*)Cp)[(long)(row + r) * N + col] = vv;
        else
          ((bf16_t*)Cp)[(long)(row + r) * N + col] = f2bf(vv);
      }
    }
}

// ---------------- causal flash attention ----------------
// Q:[S][NH*128] (roped), K:[S][NKV*128] (roped), Vt:[NKV][128][S], O:[S][NH*128]
// grid: (qt=S/64, h=NH), 256 threads (4 waves); wave w handles q rows qt*64+w*16 .. +16
__global__ __launch_bounds__(256) void attn_kernel(const bf16_t* __restrict__ Q,
                                                   const bf16_t* __restrict__ K,
                                                   const bf16_t* __restrict__ Vt,
                                                   bf16_t* __restrict__ O) {
  __shared__ __align__(16) bf16_t Ks[64 * 128];   // swizzled: byte ^= (key&7)<<4
  __shared__ __align__(16) bf16_t Vs[128 * 64];   // [d][key], swizzled: byte ^= (d&7)<<4
  __shared__ __align__(16) bf16_t Ps[4 * 16 * 88]; // per-wave P, row stride 88 elems (176B)
  const int tid = threadIdx.x, w = tid >> 6, lane = tid & 63;
  const int h = blockIdx.y, qt = blockIdx.x;
  const int kvh = h >> 2;
  const int q0 = qt * 64 + w * 16;
  const int lr = lane & 15, lkb = lane >> 4;
  const float scale = 0.08838834764831845f;  // 1/sqrt(128)

  short8 qf[4];
#pragma unroll
  for (int kb = 0; kb < 4; ++kb)
    qf[kb] = *(const short8*)(Q + (long)(q0 + lr) * HIDDEN + h * HD + kb * 32 + lkb * 8);

  float4v acc_o[8] = {};
  float mrow[4], lrow[4];
#pragma unroll
  for (int r = 0; r < 4; ++r) { mrow[r] = -1e30f; lrow[r] = 0.f; }

  for (int kt = 0; kt <= qt; ++kt) {
    __syncthreads();  // previous tile's LDS reads done
    // stage K tile [64][128]
#pragma unroll
    for (int j = 0; j < 4; ++j) {
      int c = tid + j * 256;
      int row = c >> 4, d0 = (c & 15) * 8;
      float4v kv = *(const float4v*)(K + (long)(kt * 64 + row) * (NKV * HD) + kvh * HD + d0);
      int byte = (row * 256 + d0 * 2) ^ ((row & 7) << 4);
      *(float4v*)((char*)Ks + byte) = kv;
    }
    // stage Vt tile [128][64]
#pragma unroll
    for (int j = 0; j < 4; ++j) {
      int c = tid + j * 256;
      int d = c >> 3, key0 = (c & 7) * 8;
      float4v vv = *(const float4v*)(Vt + (long)kvh * HD * SEQ + (long)d * SEQ + kt * 64 + key0);
      int byte = (d * 128 + key0 * 2) ^ ((d & 7) << 4);
      *(float4v*)((char*)Vs + byte) = vv;
    }
    __syncthreads();

    // S = Q K^T for 64 keys
    float4v accs[4] = {};
#pragma unroll
    for (int c = 0; c < 4; ++c) {
#pragma unroll
      for (int kb = 0; kb < 4; ++kb) {
        int row = c * 16 + lr;
        int byte = (row * 256 + (kb * 32 + lkb * 8) * 2) ^ ((row & 7) << 4);
        short8 kf = *(const short8*)((char*)Ks + byte);
        accs[c] = __builtin_amdgcn_mfma_f32_16x16x32_bf16(qf[kb], kf, accs[c], 0, 0, 0);
      }
    }

    const bool diag = (kt == qt);
    float p[4][4];
    float pm[4];
#pragma unroll
    for (int r = 0; r < 4; ++r) pm[r] = -1e30f;
#pragma unroll
    for (int c = 0; c < 4; ++c)
#pragma unroll
      for (int r = 0; r < 4; ++r) {
        float s = accs[c][r] * scale;
        if (diag) {
          int key = kt * 64 + c * 16 + lr;
          int qrow = q0 + lkb * 4 + r;
          if (key > qrow) s = -1e30f;
        }
        p[c][r] = s;
        pm[r] = fmaxf(pm[r], s);
      }
#pragma unroll
    for (int r = 0; r < 4; ++r) {
      float v = pm[r];
      v = fmaxf(v, __shfl_xor(v, 1));
      v = fmaxf(v, __shfl_xor(v, 2));
      v = fmaxf(v, __shfl_xor(v, 4));
      v = fmaxf(v, __shfl_xor(v, 8));
      float mnew = fmaxf(mrow[r], v);
      float alpha = __expf(mrow[r] - mnew);
      mrow[r] = mnew;
      lrow[r] *= alpha;
#pragma unroll
      for (int dj = 0; dj < 8; ++dj) acc_o[dj][r] *= alpha;
    }
    float psum[4] = {0.f, 0.f, 0.f, 0.f};
#pragma unroll
    for (int c = 0; c < 4; ++c)
#pragma unroll
      for (int r = 0; r < 4; ++r) {
        float e = __expf(p[c][r] - mrow[r]);
        p[c][r] = e;
        psum[r] += e;
      }
#pragma unroll
    for (int r = 0; r < 4; ++r) {
      float v = psum[r];
      v += __shfl_xor(v, 1);
      v += __shfl_xor(v, 2);
      v += __shfl_xor(v, 4);
      v += __shfl_xor(v, 8);
      lrow[r] += v;
    }
    // P (D-layout) -> LDS -> A-layout fragments
    bf16_t* ps = &Ps[w * 16 * 88];
#pragma unroll
    for (int c = 0; c < 4; ++c)
#pragma unroll
      for (int r = 0; r < 4; ++r)
        ps[(lkb * 4 + r) * 88 + c * 16 + lr] = f2bf(p[c][r]);
    short8 pf[2];
#pragma unroll
    for (int kb2 = 0; kb2 < 2; ++kb2)
      pf[kb2] = *(const short8*)&ps[lr * 88 + kb2 * 32 + lkb * 8];
    // O += P V
#pragma unroll
    for (int dj = 0; dj < 8; ++dj) {
#pragma unroll
      for (int kb2 = 0; kb2 < 2; ++kb2) {
        int d = dj * 16 + lr;
        int byte = (d * 128 + (kb2 * 32 + lkb * 8) * 2) ^ ((d & 7) << 4);
        short8 vf = *(const short8*)((char*)Vs + byte);
        acc_o[dj] = __builtin_amdgcn_mfma_f32_16x16x32_bf16(pf[kb2], vf, acc_o[dj], 0, 0, 0);
      }
    }
  }
  // epilogue: O = acc_o / l
#pragma unroll
  for (int dj = 0; dj < 8; ++dj)
#pragma unroll
    for (int r = 0; r < 4; ++r) {
      float v = acc_o[dj][r] / lrow[r];
      O[(long)(q0 + lkb * 4 + r) * HIDDEN + h * HD + dj * 16 + lr] = f2bf(v);
    }
}

// ---------------- launcher ----------------
extern "C" void kernel_launch(void* const* d_in, const int* in_sizes, int n_in,
                              void* d_out, int out_size, void* d_ws, size_t ws_size,
                              hipStream_t stream) {
  const float* hs  = (const float*)d_in[0];
  // d_in[1] = attention_mask (exact causal; applied analytically)
  const int* pos   = (const int*)d_in[2];
  const float* Wq  = (const float*)d_in[3];
  const float* Wk  = (const float*)d_in[4];
  const float* Wv  = (const float*)d_in[5];
  const float* Wo  = (const float*)d_in[6];
  float* out       = (float*)d_out;

  char* ws = (char*)d_ws;
  const long MB = 1024 * 1024;
  bf16_t* hsb = (bf16_t*)(ws + 0);          // 16MB  [2048][4096]
  bf16_t* wqb = (bf16_t*)(ws + 16 * MB);    // 32MB  [4096][4096]
  bf16_t* wkb = (bf16_t*)(ws + 48 * MB);    // 8MB   [1024][4096]
  bf16_t* wvb = (bf16_t*)(ws + 56 * MB);    // 8MB
  bf16_t* wob = (bf16_t*)(ws + 64 * MB);    // 32MB  [4096][4096]
  bf16_t* qb  = (bf16_t*)(ws + 96 * MB);    // 16MB  [2048][4096]
  bf16_t* kb  = (bf16_t*)(ws + 112 * MB);   // 4MB   [2048][1024]
  bf16_t* vb  = (bf16_t*)(ws + 116 * MB);   // 4MB   [2048][1024]
  bf16_t* vtb = (bf16_t*)(ws + 120 * MB);   // 4MB   [8][128][2048]
  bf16_t* aob = (bf16_t*)(ws + 124 * MB);   // 16MB  [2048][4096]
  // total 140MB of d_ws

  // 1) fp32 -> bf16
  cvt_f32_bf16<<<(SEQ * HIDDEN) / 1024, 256, 0, stream>>>(hs, hsb);
  cvt_f32_bf16<<<(HIDDEN * HIDDEN) / 1024, 256, 0, stream>>>(Wq, wqb);
  cvt_f32_bf16<<<(NKV * HD * HIDDEN) / 1024, 256, 0, stream>>>(Wk, wkb);
  cvt_f32_bf16<<<(NKV * HD * HIDDEN) / 1024, 256, 0, stream>>>(Wv, wvb);
  cvt_f32_bf16<<<(HIDDEN * HIDDEN) / 1024, 256, 0, stream>>>(Wo, wob);

  // 2) projections
  gemm_bt<0><<<dim3(HIDDEN / 128, SEQ / 128), 256, 0, stream>>>(hsb, wqb, qb, SEQ, HIDDEN, HIDDEN);
  gemm_bt<0><<<dim3((NKV * HD) / 128, SEQ / 128), 256, 0, stream>>>(hsb, wkb, kb, SEQ, NKV * HD, HIDDEN);
  gemm_bt<0><<<dim3((NKV * HD) / 128, SEQ / 128), 256, 0, stream>>>(hsb, wvb, vb, SEQ, NKV * HD, HIDDEN);

  // 3) RoPE on q and k
  rope_kernel<<<(SEQ * NH * 64) / 256, 256, 0, stream>>>(qb, pos, NH);
  rope_kernel<<<(SEQ * NKV * 64) / 256, 256, 0, stream>>>(kb, pos, NKV);

  // 4) V transpose for PV fragment layout
  transpose_v<<<dim3(SEQ / 64, (NKV * HD) / 64), 256, 0, stream>>>(vb, vtb);

  // 5) causal flash attention
  attn_kernel<<<dim3(SEQ / 64, NH), 256, 0, stream>>>(qb, kb, vtb, aob);

  // 6) output projection (fp32 out)
  gemm_bt<1><<<dim3(HIDDEN / 128, SEQ / 128), 256, 0, stream>>>(aob, wob, out, SEQ, HIDDEN, HIDDEN);
}

// Round 4
// 723.548 us; speedup vs baseline: 1.0948x; 1.0948x over previous
//
#include <hip/hip_runtime.h>
#include <stdint.h>

// Problem constants (Mistral-7B-ish attention block, B=1, S=2048)
#define HIDDEN 4096
#define SEQ    2048
#define NH     32
#define NKV    8
#define HD     128

typedef __attribute__((ext_vector_type(8))) short short8;
typedef __attribute__((ext_vector_type(4))) float float4v;
typedef __attribute__((ext_vector_type(4))) unsigned short ushort4v;
typedef unsigned short bf16_t;

__device__ __forceinline__ bf16_t f2bf(float f) {
  unsigned u = __builtin_bit_cast(unsigned, f);
  u += 0x7fff + ((u >> 16) & 1);   // RNE
  return (bf16_t)(u >> 16);
}
__device__ __forceinline__ float bf2f(bf16_t h) {
  unsigned u = ((unsigned)h) << 16;
  return __builtin_bit_cast(float, u);
}

__device__ __forceinline__ void gload_lds16(const void* g, void* l) {
  __builtin_amdgcn_global_load_lds(
      (const __attribute__((address_space(1))) unsigned int*)g,
      (__attribute__((address_space(3))) unsigned int*)l, 16, 0, 0);
}

// ---------------- fp32 -> bf16 conversion ----------------
__global__ __launch_bounds__(256) void cvt_f32_bf16(const float* __restrict__ src,
                                                    bf16_t* __restrict__ dst) {
  long i = ((long)blockIdx.x * 256 + threadIdx.x) * 4;
  float4v f = *(const float4v*)(src + i);
  ushort4v o;
  o.x = f2bf(f.x); o.y = f2bf(f.y); o.z = f2bf(f.z); o.w = f2bf(f.w);
  *(ushort4v*)(dst + i) = o;
}

// ---------------- RoPE (in place, bf16) ----------------
// x rows of [n_heads*128] at stride row_stride. pair (j, j+64).
__global__ __launch_bounds__(256) void rope_kernel(bf16_t* __restrict__ x,
                                                   const int* __restrict__ pos,
                                                   int n_heads, int row_stride) {
  long tid = (long)blockIdx.x * 256 + threadIdx.x;
  int j = (int)(tid & 63);
  long sh = tid >> 6;                 // s*n_heads + h
  int s = (int)(sh / n_heads);
  int hh = (int)(sh % n_heads);
  bf16_t* row = x + (long)s * row_stride + hh * 128;
  float f = (float)pos[s] * exp2f((float)j * (-13.28771237954945f / 64.f));
  float sn, cs;
  __sincosf(f, &sn, &cs);
  float a = bf2f(row[j]), b = bf2f(row[j + 64]);
  row[j]      = f2bf(a * cs - b * sn);
  row[j + 64] = f2bf(b * cs + a * sn);
}

// ---------------- V transpose: rows [S] x cols[1024] (at stride,off) -> [NKV][128][S] ----------------
__global__ __launch_bounds__(256) void transpose_v(const bf16_t* __restrict__ v,
                                                   bf16_t* __restrict__ vt,
                                                   int src_stride, int col_off) {
  __shared__ __align__(16) bf16_t tile[64][72];
  int s0 = blockIdx.x * 64, c0 = blockIdx.y * 64;
  int t = threadIdx.x;
#pragma unroll
  for (int j = 0; j < 8; ++j) {
    int u = j * 256 + t;                 // 2048 2-elem units
    int sl = u >> 5, dl = (u & 31) * 2;
    unsigned val = *(const unsigned*)(v + (long)(s0 + sl) * src_stride + col_off + c0 + dl);
    tile[sl][dl] = (bf16_t)(val & 0xffff);
    tile[sl][dl + 1] = (bf16_t)(val >> 16);
  }
  __syncthreads();
  int kvh = c0 >> 7, dbase = c0 & 127;
#pragma unroll
  for (int j = 0; j < 8; ++j) {
    int u = j * 256 + t;
    int dl = u >> 5, sl = (u & 31) * 2;
    unsigned val = (unsigned)tile[sl][dl] | ((unsigned)tile[sl + 1][dl] << 16);
    *(unsigned*)(vt + (long)kvh * HD * SEQ + (long)(dbase + dl) * SEQ + s0 + sl) = val;
  }
}

// ---------------- bf16 GEMM: C[M][N] = A[M][K] * B[N][K]^T ----------------
// m97-style: 128x128 tile, 4 waves (2x2 of 64x64), BK=32, global_load_lds staging.
template <int OUTF32>
__global__ __launch_bounds__(256) void gemm_bt(const bf16_t* __restrict__ A,
                                               const bf16_t* __restrict__ B,
                                               void* __restrict__ Cp,
                                               int M, int N, int K) {
  __shared__ __align__(16) bf16_t As[128 * 32];
  __shared__ __align__(16) bf16_t Bs[128 * 32];
  const int tid = threadIdx.x;
  const int w = tid >> 6, lane = tid & 63;
  const int bm = blockIdx.y, bn = blockIdx.x;
  const int wr = (w >> 1) * 64, wc = (w & 1) * 64;
  float4v acc[4][4] = {};
  const bf16_t* gA = A + (long)bm * 128 * K;
  const bf16_t* gB = B + (long)bn * 128 * K;
  const int c0 = w * 2, c1 = w * 2 + 1;
  const int rsub = lane >> 2, csub = (lane & 3) * 8;
  const int lr = lane & 15, lk = (lane >> 4) * 8;

  for (int k0 = 0; k0 < K; k0 += 32) {
    gload_lds16(gA + (long)(c0 * 16 + rsub) * K + k0 + csub, &As[c0 * 512]);
    gload_lds16(gA + (long)(c1 * 16 + rsub) * K + k0 + csub, &As[c1 * 512]);
    gload_lds16(gB + (long)(c0 * 16 + rsub) * K + k0 + csub, &Bs[c0 * 512]);
    gload_lds16(gB + (long)(c1 * 16 + rsub) * K + k0 + csub, &Bs[c1 * 512]);
    asm volatile("s_waitcnt vmcnt(0)" ::: "memory");
    __syncthreads();
    short8 af[4], bfr[4];
#pragma unroll
    for (int i = 0; i < 4; ++i)
      af[i] = *(const short8*)&As[(wr + i * 16 + lr) * 32 + lk];
#pragma unroll
    for (int i = 0; i < 4; ++i)
      bfr[i] = *(const short8*)&Bs[(wc + i * 16 + lr) * 32 + lk];
#pragma unroll
    for (int mi = 0; mi < 4; ++mi)
#pragma unroll
      for (int ni = 0; ni < 4; ++ni)
        acc[mi][ni] = __builtin_amdgcn_mfma_f32_16x16x32_bf16(af[mi], bfr[ni], acc[mi][ni], 0, 0, 0);
    __syncthreads();
  }
  const int lq = (lane >> 4) * 4;
#pragma unroll
  for (int mi = 0; mi < 4; ++mi)
#pragma unroll
    for (int ni = 0; ni < 4; ++ni) {
      int row = bm * 128 + wr + mi * 16 + lq;
      int col = bn * 128 + wc + ni * 16 + lr;
#pragma unroll
      for (int r = 0; r < 4; ++r) {
        float vv = acc[mi][ni][r];
        if (OUTF32)
          ((float*)Cp)[(long)(row + r) * N + col] = vv;
        else
          ((bf16_t*)Cp)[(long)(row + r) * N + col] = f2bf(vv);
      }
    }
}

// ---------------- causal flash attention ----------------
// Q:[S][NH*128] (roped), K: rows stride kstride with kv-heads at col kvh*128 (roped),
// Vt:[NKV][128][S], O:[S][NH*128]
// grid: (qt=S/128, h=NH), 512 threads (8 waves); wave w handles q rows qt*128+w*16 .. +16
__global__ __launch_bounds__(512, 4) void attn_kernel(const bf16_t* __restrict__ Q,
                                                      const bf16_t* __restrict__ K,
                                                      int kstride,
                                                      const bf16_t* __restrict__ Vt,
                                                      bf16_t* __restrict__ O) {
  __shared__ __align__(16) bf16_t Ks[64 * 128];    // swizzled: byte ^= (key&7)<<4
  __shared__ __align__(16) bf16_t Vs[128 * 64];    // [d][key], swizzled: byte ^= (d&7)<<4
  __shared__ __align__(16) bf16_t Ps[8 * 16 * 88]; // per-wave P, row stride 88 elems
  const int tid = threadIdx.x, w = tid >> 6, lane = tid & 63;
  const int h = blockIdx.y;
  const int x = blockIdx.x;
  const int qt = (x & 1) ? (SEQ / 128 - 1 - (x >> 1)) : (x >> 1);  // heavy/light interleave
  const int kvh = h >> 2;
  const int q0 = qt * 128 + w * 16;
  const int diag_kt = q0 >> 6;          // last key-tile this wave needs
  const int ktmax = 2 * qt + 1;         // last key-tile any wave in block needs
  const int lr = lane & 15, lkb = lane >> 4;
  const float scale = 0.08838834764831845f;  // 1/sqrt(128)

  short8 qf[4];
#pragma unroll
  for (int kb = 0; kb < 4; ++kb)
    qf[kb] = *(const short8*)(Q + (long)(q0 + lr) * HIDDEN + h * HD + kb * 32 + lkb * 8);

  float4v acc_o[8] = {};
  float mrow[4], lrow[4];
#pragma unroll
  for (int r = 0; r < 4; ++r) { mrow[r] = -1e30f; lrow[r] = 0.f; }

  for (int kt = 0; kt <= ktmax; ++kt) {
    __syncthreads();  // previous tile's LDS reads done
    // stage K tile [64][128] (512 threads, 2 x 16B each)
#pragma unroll
    for (int j = 0; j < 2; ++j) {
      int c = tid + j * 512;
      int row = c >> 4, d0 = (c & 15) * 8;
      float4v kv = *(const float4v*)(K + (long)(kt * 64 + row) * kstride + kvh * HD + d0);
      int byte = (row * 256 + d0 * 2) ^ ((row & 7) << 4);
      *(float4v*)((char*)Ks + byte) = kv;
    }
    // stage Vt tile [128][64]
#pragma unroll
    for (int j = 0; j < 2; ++j) {
      int c = tid + j * 512;
      int d = c >> 3, key0 = (c & 7) * 8;
      float4v vv = *(const float4v*)(Vt + (long)kvh * HD * SEQ + (long)d * SEQ + kt * 64 + key0);
      int byte = (d * 128 + key0 * 2) ^ ((d & 7) << 4);
      *(float4v*)((char*)Vs + byte) = vv;
    }
    __syncthreads();

    if (kt > diag_kt) continue;   // this wave's rows are fully masked beyond its diagonal

    // S = Q K^T for 64 keys
    float4v accs[4] = {};
#pragma unroll
    for (int c = 0; c < 4; ++c) {
#pragma unroll
      for (int kb = 0; kb < 4; ++kb) {
        int row = c * 16 + lr;
        int byte = (row * 256 + (kb * 32 + lkb * 8) * 2) ^ ((row & 7) << 4);
        short8 kf = *(const short8*)((char*)Ks + byte);
        accs[c] = __builtin_amdgcn_mfma_f32_16x16x32_bf16(qf[kb], kf, accs[c], 0, 0, 0);
      }
    }

    const bool diag = (kt == diag_kt);
    float p[4][4];
    float pm[4];
#pragma unroll
    for (int r = 0; r < 4; ++r) pm[r] = -1e30f;
#pragma unroll
    for (int c = 0; c < 4; ++c)
#pragma unroll
      for (int r = 0; r < 4; ++r) {
        float s = accs[c][r] * scale;
        if (diag) {
          int key = kt * 64 + c * 16 + lr;
          int qrow = q0 + lkb * 4 + r;
          if (key > qrow) s = -1e30f;
        }
        p[c][r] = s;
        pm[r] = fmaxf(pm[r], s);
      }
#pragma unroll
    for (int r = 0; r < 4; ++r) {
      float v = pm[r];
      v = fmaxf(v, __shfl_xor(v, 1));
      v = fmaxf(v, __shfl_xor(v, 2));
      v = fmaxf(v, __shfl_xor(v, 4));
      v = fmaxf(v, __shfl_xor(v, 8));
      float mnew = fmaxf(mrow[r], v);
      float alpha = __expf(mrow[r] - mnew);
      mrow[r] = mnew;
      lrow[r] *= alpha;
#pragma unroll
      for (int dj = 0; dj < 8; ++dj) acc_o[dj][r] *= alpha;
    }
    float psum[4] = {0.f, 0.f, 0.f, 0.f};
#pragma unroll
    for (int c = 0; c < 4; ++c)
#pragma unroll
      for (int r = 0; r < 4; ++r) {
        float e = __expf(p[c][r] - mrow[r]);
        p[c][r] = e;
        psum[r] += e;
      }
#pragma unroll
    for (int r = 0; r < 4; ++r) {
      float v = psum[r];
      v += __shfl_xor(v, 1);
      v += __shfl_xor(v, 2);
      v += __shfl_xor(v, 4);
      v += __shfl_xor(v, 8);
      lrow[r] += v;
    }
    // P (D-layout) -> LDS -> A-layout fragments
    bf16_t* ps = &Ps[w * 16 * 88];
#pragma unroll
    for (int c = 0; c < 4; ++c)
#pragma unroll
      for (int r = 0; r < 4; ++r)
        ps[(lkb * 4 + r) * 88 + c * 16 + lr] = f2bf(p[c][r]);
    short8 pf[2];
#pragma unroll
    for (int kb2 = 0; kb2 < 2; ++kb2)
      pf[kb2] = *(const short8*)&ps[lr * 88 + kb2 * 32 + lkb * 8];
    // O += P V
#pragma unroll
    for (int dj = 0; dj < 8; ++dj) {
#pragma unroll
      for (int kb2 = 0; kb2 < 2; ++kb2) {
        int d = dj * 16 + lr;
        int byte = (d * 128 + (kb2 * 32 + lkb * 8) * 2) ^ ((d & 7) << 4);
        short8 vf = *(const short8*)((char*)Vs + byte);
        acc_o[dj] = __builtin_amdgcn_mfma_f32_16x16x32_bf16(pf[kb2], vf, acc_o[dj], 0, 0, 0);
      }
    }
  }
  // epilogue: O = acc_o / l
#pragma unroll
  for (int dj = 0; dj < 8; ++dj)
#pragma unroll
    for (int r = 0; r < 4; ++r) {
      float v = acc_o[dj][r] / lrow[r];
      O[(long)(q0 + lkb * 4 + r) * HIDDEN + h * HD + dj * 16 + lr] = f2bf(v);
    }
}

// ---------------- launcher ----------------
extern "C" void kernel_launch(void* const* d_in, const int* in_sizes, int n_in,
                              void* d_out, int out_size, void* d_ws, size_t ws_size,
                              hipStream_t stream) {
  const float* hs  = (const float*)d_in[0];
  // d_in[1] = attention_mask (exact causal; applied analytically)
  const int* pos   = (const int*)d_in[2];
  const float* Wq  = (const float*)d_in[3];
  const float* Wk  = (const float*)d_in[4];
  const float* Wv  = (const float*)d_in[5];
  const float* Wo  = (const float*)d_in[6];
  float* out       = (float*)d_out;

  char* ws = (char*)d_ws;
  const long MB = 1024 * 1024;
  bf16_t* hsb  = (bf16_t*)(ws + 0);          // 16MB  [2048][4096]
  bf16_t* wqb  = (bf16_t*)(ws + 16 * MB);    // 32MB  [4096][4096]
  bf16_t* wkvb = (bf16_t*)(ws + 48 * MB);    // 16MB  [2048][4096] (Wk rows then Wv rows)
  bf16_t* wob  = (bf16_t*)(ws + 64 * MB);    // 32MB  [4096][4096]
  bf16_t* qb   = (bf16_t*)(ws + 96 * MB);    // 16MB  [2048][4096]
  bf16_t* kvb  = (bf16_t*)(ws + 112 * MB);   // 8MB   [2048][2048] (K cols 0..1023, V cols 1024..2047)
  bf16_t* vtb  = (bf16_t*)(ws + 120 * MB);   // 4MB   [8][128][2048]
  bf16_t* aob  = (bf16_t*)(ws + 124 * MB);   // 16MB  [2048][4096]
  // total 140MB of d_ws

  // 1) fp32 -> bf16
  cvt_f32_bf16<<<(SEQ * HIDDEN) / 1024, 256, 0, stream>>>(hs, hsb);
  cvt_f32_bf16<<<(HIDDEN * HIDDEN) / 1024, 256, 0, stream>>>(Wq, wqb);
  cvt_f32_bf16<<<(NKV * HD * HIDDEN) / 1024, 256, 0, stream>>>(Wk, wkvb);
  cvt_f32_bf16<<<(NKV * HD * HIDDEN) / 1024, 256, 0, stream>>>(Wv, wkvb + (long)NKV * HD * HIDDEN);
  cvt_f32_bf16<<<(HIDDEN * HIDDEN) / 1024, 256, 0, stream>>>(Wo, wob);

  // 2) projections (K and V fused: N=2048)
  gemm_bt<0><<<dim3(HIDDEN / 128, SEQ / 128), 256, 0, stream>>>(hsb, wqb, qb, SEQ, HIDDEN, HIDDEN);
  gemm_bt<0><<<dim3((2 * NKV * HD) / 128, SEQ / 128), 256, 0, stream>>>(hsb, wkvb, kvb, SEQ, 2 * NKV * HD, HIDDEN);

  // 3) RoPE on q and k
  rope_kernel<<<(SEQ * NH * 64) / 256, 256, 0, stream>>>(qb, pos, NH, HIDDEN);
  rope_kernel<<<(SEQ * NKV * 64) / 256, 256, 0, stream>>>(kvb, pos, NKV, 2 * NKV * HD);

  // 4) V transpose for PV fragment layout (V lives at col offset 1024 in kvb)
  transpose_v<<<dim3(SEQ / 64, (NKV * HD) / 64), 256, 0, stream>>>(kvb, vtb, 2 * NKV * HD, NKV * HD);

  // 5) causal flash attention (128 q-rows per block, 8 waves)
  attn_kernel<<<dim3(SEQ / 128, NH), 512, 0, stream>>>(qb, kvb, 2 * NKV * HD, vtb, aob);

  // 6) output projection (fp32 out)
  gemm_bt<1><<<dim3(HIDDEN / 128, SEQ / 128), 256, 0, stream>>>(aob, wob, out, SEQ, HIDDEN, HIDDEN);
}

// Round 5
// 622.289 us; speedup vs baseline: 1.2729x; 1.1627x over previous
//
#include <hip/hip_runtime.h>
#include <stdint.h>

// Problem constants (Mistral-7B-ish attention block, B=1, S=2048)
#define HIDDEN 4096
#define SEQ    2048
#define NH     32
#define NKV    8
#define HD     128
#define QKVN   (HIDDEN + 2 * NKV * HD)   // 6144 fused projection width

typedef __attribute__((ext_vector_type(8))) short short8;
typedef __attribute__((ext_vector_type(4))) float float4v;
typedef __attribute__((ext_vector_type(4))) unsigned short ushort4v;
typedef unsigned short bf16_t;

__device__ __forceinline__ bf16_t f2bf(float f) {
  unsigned u = __builtin_bit_cast(unsigned, f);
  u += 0x7fff + ((u >> 16) & 1);   // RNE
  return (bf16_t)(u >> 16);
}
__device__ __forceinline__ float bf2f(bf16_t h) {
  unsigned u = ((unsigned)h) << 16;
  return __builtin_bit_cast(float, u);
}

__device__ __forceinline__ void gload_lds16(const void* g, void* l) {
  __builtin_amdgcn_global_load_lds(
      (const __attribute__((address_space(1))) unsigned int*)g,
      (__attribute__((address_space(3))) unsigned int*)l, 16, 0, 0);
}

// ---------------- fp32 -> bf16 conversion ----------------
__global__ __launch_bounds__(256) void cvt_f32_bf16(const float* __restrict__ src,
                                                    bf16_t* __restrict__ dst) {
  long i = ((long)blockIdx.x * 256 + threadIdx.x) * 4;
  float4v f = *(const float4v*)(src + i);
  ushort4v o;
  o.x = f2bf(f.x); o.y = f2bf(f.y); o.z = f2bf(f.z); o.w = f2bf(f.w);
  *(ushort4v*)(dst + i) = o;
}

// ---------------- RoPE (in place, bf16) ----------------
// x rows of [n_heads*128] at stride row_stride (x may carry a col offset). pair (j, j+64).
__global__ __launch_bounds__(256) void rope_kernel(bf16_t* __restrict__ x,
                                                   const int* __restrict__ pos,
                                                   int n_heads, int row_stride) {
  long tid = (long)blockIdx.x * 256 + threadIdx.x;
  int j = (int)(tid & 63);
  long sh = tid >> 6;                 // s*n_heads + h
  int s = (int)(sh / n_heads);
  int hh = (int)(sh % n_heads);
  bf16_t* row = x + (long)s * row_stride + hh * 128;
  float f = (float)pos[s] * exp2f((float)j * (-13.28771237954945f / 64.f));
  float sn, cs;
  __sincosf(f, &sn, &cs);
  float a = bf2f(row[j]), b = bf2f(row[j + 64]);
  row[j]      = f2bf(a * cs - b * sn);
  row[j + 64] = f2bf(b * cs + a * sn);
}

// ---------------- V transpose: rows [S] x cols[1024] (at stride,off) -> [NKV][128][S] ----------------
__global__ __launch_bounds__(256) void transpose_v(const bf16_t* __restrict__ v,
                                                   bf16_t* __restrict__ vt,
                                                   int src_stride, int col_off) {
  __shared__ __align__(16) bf16_t tile[64][72];
  int s0 = blockIdx.x * 64, c0 = blockIdx.y * 64;
  int t = threadIdx.x;
#pragma unroll
  for (int j = 0; j < 8; ++j) {
    int u = j * 256 + t;                 // 2048 2-elem units
    int sl = u >> 5, dl = (u & 31) * 2;
    unsigned val = *(const unsigned*)(v + (long)(s0 + sl) * src_stride + col_off + c0 + dl);
    tile[sl][dl] = (bf16_t)(val & 0xffff);
    tile[sl][dl + 1] = (bf16_t)(val >> 16);
  }
  __syncthreads();
  int kvh = c0 >> 7, dbase = c0 & 127;
#pragma unroll
  for (int j = 0; j < 8; ++j) {
    int u = j * 256 + t;
    int dl = u >> 5, sl = (u & 31) * 2;
    unsigned val = (unsigned)tile[sl][dl] | ((unsigned)tile[sl + 1][dl] << 16);
    *(unsigned*)(vt + (long)kvh * HD * SEQ + (long)(dbase + dl) * SEQ + s0 + sl) = val;
  }
}

// ---------------- bf16 GEMM: C[M][N] = A[M][K] * B[N][K]^T ----------------
// m97-style: 128x128 tile, 4 waves (2x2 of 64x64), BK=32, global_load_lds staging.
template <int OUTF32>
__global__ __launch_bounds__(256) void gemm_bt(const bf16_t* __restrict__ A,
                                               const bf16_t* __restrict__ B,
                                               void* __restrict__ Cp,
                                               int M, int N, int K) {
  __shared__ __align__(16) bf16_t As[128 * 32];
  __shared__ __align__(16) bf16_t Bs[128 * 32];
  const int tid = threadIdx.x;
  const int w = tid >> 6, lane = tid & 63;
  const int bm = blockIdx.y, bn = blockIdx.x;
  const int wr = (w >> 1) * 64, wc = (w & 1) * 64;
  float4v acc[4][4] = {};
  const bf16_t* gA = A + (long)bm * 128 * K;
  const bf16_t* gB = B + (long)bn * 128 * K;
  const int c0 = w * 2, c1 = w * 2 + 1;
  const int rsub = lane >> 2, csub = (lane & 3) * 8;
  const int lr = lane & 15, lk = (lane >> 4) * 8;

  for (int k0 = 0; k0 < K; k0 += 32) {
    gload_lds16(gA + (long)(c0 * 16 + rsub) * K + k0 + csub, &As[c0 * 512]);
    gload_lds16(gA + (long)(c1 * 16 + rsub) * K + k0 + csub, &As[c1 * 512]);
    gload_lds16(gB + (long)(c0 * 16 + rsub) * K + k0 + csub, &Bs[c0 * 512]);
    gload_lds16(gB + (long)(c1 * 16 + rsub) * K + k0 + csub, &Bs[c1 * 512]);
    asm volatile("s_waitcnt vmcnt(0)" ::: "memory");
    __syncthreads();
    short8 af[4], bfr[4];
#pragma unroll
    for (int i = 0; i < 4; ++i)
      af[i] = *(const short8*)&As[(wr + i * 16 + lr) * 32 + lk];
#pragma unroll
    for (int i = 0; i < 4; ++i)
      bfr[i] = *(const short8*)&Bs[(wc + i * 16 + lr) * 32 + lk];
#pragma unroll
    for (int mi = 0; mi < 4; ++mi)
#pragma unroll
      for (int ni = 0; ni < 4; ++ni)
        acc[mi][ni] = __builtin_amdgcn_mfma_f32_16x16x32_bf16(af[mi], bfr[ni], acc[mi][ni], 0, 0, 0);
    __syncthreads();
  }
  const int lq = (lane >> 4) * 4;
#pragma unroll
  for (int mi = 0; mi < 4; ++mi)
#pragma unroll
    for (int ni = 0; ni < 4; ++ni) {
      int row = bm * 128 + wr + mi * 16 + lq;
      int col = bn * 128 + wc + ni * 16 + lr;
#pragma unroll
      for (int r = 0; r < 4; ++r) {
        float vv = acc[mi][ni][r];
        if (OUTF32)
          ((float*)Cp)[(long)(row + r) * N + col] = vv;
        else
          ((bf16_t*)Cp)[(long)(row + r) * N + col] = f2bf(vv);
      }
    }
}

// ---------------- causal flash attention ----------------
// QKV:[S][6144] (roped). Q at col h*128; K at col 4096+kvh*128. Vt:[NKV][128][S].
// O:[S][4096]. grid (qt=S/128, h=NH), 256 threads (4 waves);
// wave w owns 32 q-rows: qt*128 + w*32 .. +32, as two 16-row subtiles.
__global__ __launch_bounds__(256, 2) void attn_kernel(const bf16_t* __restrict__ QKV,
                                                      const bf16_t* __restrict__ Vt,
                                                      bf16_t* __restrict__ O) {
  __shared__ __align__(16) bf16_t Ks[64 * 128];    // swizzled: byte ^= (key&7)<<4
  __shared__ __align__(16) bf16_t Vs[128 * 64];    // [d][key], swizzled: byte ^= (d&7)<<4
  __shared__ __align__(16) bf16_t Ps[4 * 16 * 88]; // per-wave P, row stride 88 elems
  const int tid = threadIdx.x, w = tid >> 6, lane = tid & 63;
  const int h = blockIdx.y;
  const int x = blockIdx.x;
  const int qt = (x & 1) ? (SEQ / 128 - 1 - (x >> 1)) : (x >> 1);  // heavy/light interleave
  const int kvh = h >> 2;
  const int q0 = qt * 128 + w * 32;     // first of this wave's 32 rows
  const int ktmax = 2 * qt + 1;         // last key-tile any wave in block needs
  const int lr = lane & 15, lkb = lane >> 4;
  const float scale = 0.08838834764831845f;  // 1/sqrt(128)
  const bf16_t* Kbase = QKV + HIDDEN + kvh * HD;   // K cols start at 4096

  short8 qf[2][4];
#pragma unroll
  for (int qs = 0; qs < 2; ++qs)
#pragma unroll
    for (int kb = 0; kb < 4; ++kb)
      qf[qs][kb] = *(const short8*)(QKV + (long)(q0 + qs * 16 + lr) * QKVN + h * HD + kb * 32 + lkb * 8);

  float4v acc_o[2][8] = {};
  float mrow[2][4], lrow[2][4];
#pragma unroll
  for (int qs = 0; qs < 2; ++qs)
#pragma unroll
    for (int r = 0; r < 4; ++r) { mrow[qs][r] = -1e30f; lrow[qs][r] = 0.f; }

  for (int kt = 0; kt <= ktmax; ++kt) {
    __syncthreads();  // previous tile's LDS reads done
    // stage K tile [64][128] (256 threads, 4 x 16B each)
#pragma unroll
    for (int j = 0; j < 4; ++j) {
      int c = tid + j * 256;
      int row = c >> 4, d0 = (c & 15) * 8;
      float4v kv = *(const float4v*)(Kbase + (long)(kt * 64 + row) * QKVN + d0);
      int byte = (row * 256 + d0 * 2) ^ ((row & 7) << 4);
      *(float4v*)((char*)Ks + byte) = kv;
    }
    // stage Vt tile [128][64]
#pragma unroll
    for (int j = 0; j < 4; ++j) {
      int c = tid + j * 256;
      int d = c >> 3, key0 = (c & 7) * 8;
      float4v vv = *(const float4v*)(Vt + (long)kvh * HD * SEQ + (long)d * SEQ + kt * 64 + key0);
      int byte = (d * 128 + key0 * 2) ^ ((d & 7) << 4);
      *(float4v*)((char*)Vs + byte) = vv;
    }
    __syncthreads();

#pragma unroll
    for (int qs = 0; qs < 2; ++qs) {
      const int q0s = q0 + qs * 16;
      const int st_kt = q0s >> 6;       // this subtile's diagonal key-tile
      if (kt > st_kt) continue;         // fully masked

      // S = Q K^T for 64 keys
      float4v accs[4] = {};
      __builtin_amdgcn_s_setprio(1);
#pragma unroll
      for (int c = 0; c < 4; ++c) {
#pragma unroll
        for (int kb = 0; kb < 4; ++kb) {
          int row = c * 16 + lr;
          int byte = (row * 256 + (kb * 32 + lkb * 8) * 2) ^ ((row & 7) << 4);
          short8 kf = *(const short8*)((char*)Ks + byte);
          accs[c] = __builtin_amdgcn_mfma_f32_16x16x32_bf16(qf[qs][kb], kf, accs[c], 0, 0, 0);
        }
      }
      __builtin_amdgcn_s_setprio(0);

      const bool diag = (kt == st_kt);
      float p[4][4];
      float pm[4];
#pragma unroll
      for (int r = 0; r < 4; ++r) pm[r] = -1e30f;
#pragma unroll
      for (int c = 0; c < 4; ++c)
#pragma unroll
        for (int r = 0; r < 4; ++r) {
          float s = accs[c][r] * scale;
          if (diag) {
            int key = kt * 64 + c * 16 + lr;
            int qrow = q0s + lkb * 4 + r;
            if (key > qrow) s = -1e30f;
          }
          p[c][r] = s;
          pm[r] = fmaxf(pm[r], s);
        }
#pragma unroll
      for (int r = 0; r < 4; ++r) {
        float v = pm[r];
        v = fmaxf(v, __shfl_xor(v, 1));
        v = fmaxf(v, __shfl_xor(v, 2));
        v = fmaxf(v, __shfl_xor(v, 4));
        v = fmaxf(v, __shfl_xor(v, 8));
        float mnew = fmaxf(mrow[qs][r], v);
        float alpha = __expf(mrow[qs][r] - mnew);
        mrow[qs][r] = mnew;
        lrow[qs][r] *= alpha;
#pragma unroll
        for (int dj = 0; dj < 8; ++dj) acc_o[qs][dj][r] *= alpha;
      }
      float psum[4] = {0.f, 0.f, 0.f, 0.f};
#pragma unroll
      for (int c = 0; c < 4; ++c)
#pragma unroll
        for (int r = 0; r < 4; ++r) {
          float e = __expf(p[c][r] - mrow[qs][r]);
          p[c][r] = e;
          psum[r] += e;
        }
#pragma unroll
      for (int r = 0; r < 4; ++r) {
        float v = psum[r];
        v += __shfl_xor(v, 1);
        v += __shfl_xor(v, 2);
        v += __shfl_xor(v, 4);
        v += __shfl_xor(v, 8);
        lrow[qs][r] += v;
      }
      // P (D-layout) -> LDS -> A-layout fragments (within-wave, no barrier needed)
      bf16_t* ps = &Ps[w * 16 * 88];
#pragma unroll
      for (int c = 0; c < 4; ++c)
#pragma unroll
        for (int r = 0; r < 4; ++r)
          ps[(lkb * 4 + r) * 88 + c * 16 + lr] = f2bf(p[c][r]);
      short8 pf[2];
#pragma unroll
      for (int kb2 = 0; kb2 < 2; ++kb2)
        pf[kb2] = *(const short8*)&ps[lr * 88 + kb2 * 32 + lkb * 8];
      // O += P V
      __builtin_amdgcn_s_setprio(1);
#pragma unroll
      for (int dj = 0; dj < 8; ++dj) {
#pragma unroll
        for (int kb2 = 0; kb2 < 2; ++kb2) {
          int d = dj * 16 + lr;
          int byte = (d * 128 + (kb2 * 32 + lkb * 8) * 2) ^ ((d & 7) << 4);
          short8 vf = *(const short8*)((char*)Vs + byte);
          acc_o[qs][dj] = __builtin_amdgcn_mfma_f32_16x16x32_bf16(pf[kb2], vf, acc_o[qs][dj], 0, 0, 0);
        }
      }
      __builtin_amdgcn_s_setprio(0);
    }
  }
  // epilogue: O = acc_o / l
#pragma unroll
  for (int qs = 0; qs < 2; ++qs)
#pragma unroll
    for (int dj = 0; dj < 8; ++dj)
#pragma unroll
      for (int r = 0; r < 4; ++r) {
        float v = acc_o[qs][dj][r] / lrow[qs][r];
        O[(long)(q0 + qs * 16 + lkb * 4 + r) * HIDDEN + h * HD + dj * 16 + lr] = f2bf(v);
      }
}

// ---------------- launcher ----------------
extern "C" void kernel_launch(void* const* d_in, const int* in_sizes, int n_in,
                              void* d_out, int out_size, void* d_ws, size_t ws_size,
                              hipStream_t stream) {
  const float* hs  = (const float*)d_in[0];
  // d_in[1] = attention_mask (exact causal; applied analytically)
  const int* pos   = (const int*)d_in[2];
  const float* Wq  = (const float*)d_in[3];
  const float* Wk  = (const float*)d_in[4];
  const float* Wv  = (const float*)d_in[5];
  const float* Wo  = (const float*)d_in[6];
  float* out       = (float*)d_out;

  char* ws = (char*)d_ws;
  const long MB = 1024 * 1024;
  bf16_t* hsb   = (bf16_t*)(ws + 0);          // 16MB  [2048][4096]
  bf16_t* wqkvb = (bf16_t*)(ws + 16 * MB);    // 48MB  [6144][4096]: Wq | Wk | Wv rows
  bf16_t* wob   = (bf16_t*)(ws + 64 * MB);    // 32MB  [4096][4096]
  bf16_t* qkvb  = (bf16_t*)(ws + 96 * MB);    // 24MB  [2048][6144]
  bf16_t* vtb   = (bf16_t*)(ws + 120 * MB);   // 4MB   [8][128][2048]
  bf16_t* aob   = (bf16_t*)(ws + 124 * MB);   // 16MB  [2048][4096]
  // total 140MB of d_ws

  // 1) fp32 -> bf16 (Wq/Wk/Wv stacked into one [6144][4096] weight)
  cvt_f32_bf16<<<(SEQ * HIDDEN) / 1024, 256, 0, stream>>>(hs, hsb);
  cvt_f32_bf16<<<(HIDDEN * HIDDEN) / 1024, 256, 0, stream>>>(Wq, wqkvb);
  cvt_f32_bf16<<<(NKV * HD * HIDDEN) / 1024, 256, 0, stream>>>(Wk, wqkvb + (long)HIDDEN * HIDDEN);
  cvt_f32_bf16<<<(NKV * HD * HIDDEN) / 1024, 256, 0, stream>>>(Wv, wqkvb + (long)(HIDDEN + NKV * HD) * HIDDEN);
  cvt_f32_bf16<<<(HIDDEN * HIDDEN) / 1024, 256, 0, stream>>>(Wo, wob);

  // 2) fused QKV projection: [2048][6144]
  gemm_bt<0><<<dim3(QKVN / 128, SEQ / 128), 256, 0, stream>>>(hsb, wqkvb, qkvb, SEQ, QKVN, HIDDEN);

  // 3) RoPE on Q (cols 0..4095) and K (cols 4096..5119)
  rope_kernel<<<(SEQ * NH * 64) / 256, 256, 0, stream>>>(qkvb, pos, NH, QKVN);
  rope_kernel<<<(SEQ * NKV * 64) / 256, 256, 0, stream>>>(qkvb + HIDDEN, pos, NKV, QKVN);

  // 4) V transpose (V at col offset 5120 in qkvb)
  transpose_v<<<dim3(SEQ / 64, (NKV * HD) / 64), 256, 0, stream>>>(qkvb, vtb, QKVN, HIDDEN + NKV * HD);

  // 5) causal flash attention (128 q-rows per block, 4 waves x 32 rows)
  attn_kernel<<<dim3(SEQ / 128, NH), 256, 0, stream>>>(qkvb, vtb, aob);

  // 6) output projection (fp32 out)
  gemm_bt<1><<<dim3(HIDDEN / 128, SEQ / 128), 256, 0, stream>>>(aob, wob, out, SEQ, HIDDEN, HIDDEN);
}

// Round 6
// 575.802 us; speedup vs baseline: 1.3757x; 1.0807x over previous
//
#include <hip/hip_runtime.h>
#include <stdint.h>

// Problem constants (Mistral-7B-ish attention block, B=1, S=2048)
#define HIDDEN 4096
#define SEQ    2048
#define NH     32
#define NKV    8
#define HD     128
#define QKVN   (HIDDEN + 2 * NKV * HD)   // 6144 fused projection width
#define NTASK  512

typedef __attribute__((ext_vector_type(8))) short short8;
typedef __attribute__((ext_vector_type(4))) float float4v;
typedef __attribute__((ext_vector_type(4))) unsigned short ushort4v;
typedef __attribute__((ext_vector_type(2))) unsigned int uint2v;
typedef unsigned short bf16_t;

__device__ __forceinline__ bf16_t f2bf(float f) {
  unsigned u = __builtin_bit_cast(unsigned, f);
  u += 0x7fff + ((u >> 16) & 1);   // RNE
  return (bf16_t)(u >> 16);
}
__device__ __forceinline__ float bf2f(bf16_t h) {
  unsigned u = ((unsigned)h) << 16;
  return __builtin_bit_cast(float, u);
}
__device__ __forceinline__ unsigned cvt_pk_bf16(float lo, float hi) {
  unsigned r;
  asm("v_cvt_pk_bf16_f32 %0, %1, %2" : "=v"(r) : "v"(lo), "v"(hi));
  return r;
}

__device__ __forceinline__ void gload_lds16(const void* g, void* l) {
  __builtin_amdgcn_global_load_lds(
      (const __attribute__((address_space(1))) unsigned int*)g,
      (__attribute__((address_space(3))) unsigned int*)l, 16, 0, 0);
}

// ---------------- fp32 -> bf16 conversion ----------------
__global__ __launch_bounds__(256) void cvt_f32_bf16(const float* __restrict__ src,
                                                    bf16_t* __restrict__ dst) {
  long i = ((long)blockIdx.x * 256 + threadIdx.x) * 4;
  float4v f = *(const float4v*)(src + i);
  ushort4v o;
  o.x = f2bf(f.x); o.y = f2bf(f.y); o.z = f2bf(f.z); o.w = f2bf(f.w);
  *(ushort4v*)(dst + i) = o;
}

// ---------------- RoPE (in place, bf16) ----------------
__global__ __launch_bounds__(256) void rope_kernel(bf16_t* __restrict__ x,
                                                   const int* __restrict__ pos,
                                                   int n_heads, int row_stride) {
  long tid = (long)blockIdx.x * 256 + threadIdx.x;
  int j = (int)(tid & 63);
  long sh = tid >> 6;
  int s = (int)(sh / n_heads);
  int hh = (int)(sh % n_heads);
  bf16_t* row = x + (long)s * row_stride + hh * 128;
  float f = (float)pos[s] * exp2f((float)j * (-13.28771237954945f / 64.f));
  float sn, cs;
  __sincosf(f, &sn, &cs);
  float a = bf2f(row[j]), b = bf2f(row[j + 64]);
  row[j]      = f2bf(a * cs - b * sn);
  row[j + 64] = f2bf(b * cs + a * sn);
}

// ---------------- V transpose -> [NKV][128][S] ----------------
__global__ __launch_bounds__(256) void transpose_v(const bf16_t* __restrict__ v,
                                                   bf16_t* __restrict__ vt,
                                                   int src_stride, int col_off) {
  __shared__ __align__(16) bf16_t tile[64][72];
  int s0 = blockIdx.x * 64, c0 = blockIdx.y * 64;
  int t = threadIdx.x;
#pragma unroll
  for (int j = 0; j < 8; ++j) {
    int u = j * 256 + t;
    int sl = u >> 5, dl = (u & 31) * 2;
    unsigned val = *(const unsigned*)(v + (long)(s0 + sl) * src_stride + col_off + c0 + dl);
    tile[sl][dl] = (bf16_t)(val & 0xffff);
    tile[sl][dl + 1] = (bf16_t)(val >> 16);
  }
  __syncthreads();
  int kvh = c0 >> 7, dbase = c0 & 127;
#pragma unroll
  for (int j = 0; j < 8; ++j) {
    int u = j * 256 + t;
    int dl = u >> 5, sl = (u & 31) * 2;
    unsigned val = (unsigned)tile[sl][dl] | ((unsigned)tile[sl + 1][dl] << 16);
    *(unsigned*)(vt + (long)kvh * HD * SEQ + (long)(dbase + dl) * SEQ + s0 + sl) = val;
  }
}

// ---------------- bf16 GEMM: C[M][N] = A[M][K] * B[N][K]^T ----------------
template <int OUTF32>
__global__ __launch_bounds__(256) void gemm_bt(const bf16_t* __restrict__ A,
                                               const bf16_t* __restrict__ B,
                                               void* __restrict__ Cp,
                                               int M, int N, int K) {
  __shared__ __align__(16) bf16_t As[128 * 32];
  __shared__ __align__(16) bf16_t Bs[128 * 32];
  const int tid = threadIdx.x;
  const int w = tid >> 6, lane = tid & 63;
  const int bm = blockIdx.y, bn = blockIdx.x;
  const int wr = (w >> 1) * 64, wc = (w & 1) * 64;
  float4v acc[4][4] = {};
  const bf16_t* gA = A + (long)bm * 128 * K;
  const bf16_t* gB = B + (long)bn * 128 * K;
  const int c0 = w * 2, c1 = w * 2 + 1;
  const int rsub = lane >> 2, csub = (lane & 3) * 8;
  const int lr = lane & 15, lk = (lane >> 4) * 8;

  for (int k0 = 0; k0 < K; k0 += 32) {
    gload_lds16(gA + (long)(c0 * 16 + rsub) * K + k0 + csub, &As[c0 * 512]);
    gload_lds16(gA + (long)(c1 * 16 + rsub) * K + k0 + csub, &As[c1 * 512]);
    gload_lds16(gB + (long)(c0 * 16 + rsub) * K + k0 + csub, &Bs[c0 * 512]);
    gload_lds16(gB + (long)(c1 * 16 + rsub) * K + k0 + csub, &Bs[c1 * 512]);
    asm volatile("s_waitcnt vmcnt(0)" ::: "memory");
    __syncthreads();
    short8 af[4], bfr[4];
#pragma unroll
    for (int i = 0; i < 4; ++i)
      af[i] = *(const short8*)&As[(wr + i * 16 + lr) * 32 + lk];
#pragma unroll
    for (int i = 0; i < 4; ++i)
      bfr[i] = *(const short8*)&Bs[(wc + i * 16 + lr) * 32 + lk];
#pragma unroll
    for (int mi = 0; mi < 4; ++mi)
#pragma unroll
      for (int ni = 0; ni < 4; ++ni)
        acc[mi][ni] = __builtin_amdgcn_mfma_f32_16x16x32_bf16(af[mi], bfr[ni], acc[mi][ni], 0, 0, 0);
    __syncthreads();
  }
  const int lq = (lane >> 4) * 4;
#pragma unroll
  for (int mi = 0; mi < 4; ++mi)
#pragma unroll
    for (int ni = 0; ni < 4; ++ni) {
      int row = bm * 128 + wr + mi * 16 + lq;
      int col = bn * 128 + wc + ni * 16 + lr;
#pragma unroll
      for (int r = 0; r < 4; ++r) {
        float vv = acc[mi][ni][r];
        if (OUTF32)
          ((float*)Cp)[(long)(row + r) * N + col] = vv;
        else
          ((bf16_t*)Cp)[(long)(row + r) * N + col] = f2bf(vv);
      }
    }
}

// ---------------- causal flash attention (persistent, LPT queue) ----------------
// Swapped-operand scheme: QK^T computed as mfma(K,Q) -> accs[key][q] (q = lane&15),
// PV computed as mfma(V,P) -> acc_o[d][q]. Softmax is per-lane scalar (one q-row).
// Tasks: t in [0,512): qt = 15 - t/32 (heavy-first), h = t%32. 512 persistent blocks.
__global__ __launch_bounds__(256, 2) void attn_kernel(const bf16_t* __restrict__ QKV,
                                                      const bf16_t* __restrict__ Vt,
                                                      bf16_t* __restrict__ O,
                                                      int* __restrict__ ctr) {
  __shared__ __align__(16) bf16_t Ks[64 * 128];    // [key][d], byte ^= (key&7)<<4
  __shared__ __align__(16) bf16_t Vs[128 * 64];    // [d][key], byte ^= (d&7)<<4
  __shared__ __align__(16) bf16_t Ps[8][16 * 72];  // [w*2+qs][q][key], byte ^= (q&1)<<4
  __shared__ int s_task;
  const int tid = threadIdx.x, w = tid >> 6, lane = tid & 63;
  const int lr = lane & 15, g = lane >> 4;
  const float kscale = 0.1275310246f;  // log2(e)/sqrt(128)

  for (;;) {
    __syncthreads();                       // protect s_task + LDS across tasks
    if (tid == 0) s_task = atomicAdd(ctr, 1);
    __syncthreads();
    const int t = s_task;
    if (t >= NTASK) return;                // uniform exit
    const int qt = 15 - (t >> 5);
    const int h = t & 31, kvh = h >> 2;
    const int q0 = qt * 128 + w * 32;      // this wave's 32 q-rows
    const int st_kt = q0 >> 6;             // same diag tile for both 16-row subtiles
    const int ktmax = 2 * qt + 1;
    const bf16_t* Kb = QKV + HIDDEN + kvh * HD;
    const bf16_t* Vb = Vt + (long)kvh * HD * SEQ;

    short8 qf[2][4];
#pragma unroll
    for (int qs = 0; qs < 2; ++qs)
#pragma unroll
      for (int kb = 0; kb < 4; ++kb)
        qf[qs][kb] = *(const short8*)(QKV + (long)(q0 + qs * 16 + lr) * QKVN + h * HD + kb * 32 + g * 8);

    float4v acc_o[2][8] = {};
    float mrow[2] = {-1e30f, -1e30f}, lrow[2] = {0.f, 0.f};

    for (int kt = 0; kt <= ktmax; ++kt) {
      __syncthreads();
      // stage K tile [64][128]
#pragma unroll
      for (int j = 0; j < 4; ++j) {
        int c = tid + j * 256;
        int row = c >> 4, d0 = (c & 15) * 8;
        float4v kv = *(const float4v*)(Kb + (long)(kt * 64 + row) * QKVN + d0);
        int byte = (row * 256 + d0 * 2) ^ ((row & 7) << 4);
        *(float4v*)((char*)Ks + byte) = kv;
      }
      // stage Vt tile [128][64]
#pragma unroll
      for (int j = 0; j < 4; ++j) {
        int c = tid + j * 256;
        int d = c >> 3, key0 = (c & 7) * 8;
        float4v vv = *(const float4v*)(Vb + (long)d * SEQ + kt * 64 + key0);
        int byte = (d * 128 + key0 * 2) ^ ((d & 7) << 4);
        *(float4v*)((char*)Vs + byte) = vv;
      }
      __syncthreads();

      if (kt > st_kt) continue;            // whole wave masked beyond its diagonal
      const bool diag = (kt == st_kt);

      // S = K Q^T : accs[qs][c] holds S[key = c*16 + g*4 + r][q = lr]
      float4v accs[2][4] = {};
      __builtin_amdgcn_s_setprio(1);
#pragma unroll
      for (int c = 0; c < 4; ++c) {
#pragma unroll
        for (int kb = 0; kb < 4; ++kb) {
          int row = c * 16 + lr;
          int byte = (row * 256 + (kb * 32 + g * 8) * 2) ^ ((row & 7) << 4);
          short8 kf = *(const short8*)((char*)Ks + byte);
          accs[0][c] = __builtin_amdgcn_mfma_f32_16x16x32_bf16(kf, qf[0][kb], accs[0][c], 0, 0, 0);
          accs[1][c] = __builtin_amdgcn_mfma_f32_16x16x32_bf16(kf, qf[1][kb], accs[1][c], 0, 0, 0);
        }
      }
      __builtin_amdgcn_s_setprio(0);

      short8 pf[2][2];
#pragma unroll
      for (int qs = 0; qs < 2; ++qs) {
        const int qrow = q0 + qs * 16 + lr;
        float p[4][4];
        float pm = -1e30f;
#pragma unroll
        for (int c = 0; c < 4; ++c)
#pragma unroll
          for (int r = 0; r < 4; ++r) {
            float s = accs[qs][c][r] * kscale;
            if (diag) {
              int key = kt * 64 + c * 16 + g * 4 + r;
              if (key > qrow) s = -1e30f;
            }
            p[c][r] = s;
            pm = fmaxf(pm, s);
          }
        pm = fmaxf(pm, __shfl_xor(pm, 16));
        pm = fmaxf(pm, __shfl_xor(pm, 32));
        if (__any(pm > mrow[qs] + 11.5f)) {         // defer-max (THR = 8 nats)
          float mnew = fmaxf(mrow[qs], pm);
          float alpha = exp2f(mrow[qs] - mnew);
          mrow[qs] = mnew;
          lrow[qs] *= alpha;
#pragma unroll
          for (int dj = 0; dj < 8; ++dj) acc_o[qs][dj] *= alpha;
        }
        float psum = 0.f;
#pragma unroll
        for (int c = 0; c < 4; ++c)
#pragma unroll
          for (int r = 0; r < 4; ++r) {
            float e = exp2f(p[c][r] - mrow[qs]);
            p[c][r] = e;
            psum += e;
          }
        psum += __shfl_xor(psum, 16);
        psum += __shfl_xor(psum, 32);
        lrow[qs] += psum;
        // pack P -> Ps[q][key] (b64 writes), then read A.. B-fragments (b128)
        char* psB = (char*)Ps[w * 2 + qs];
#pragma unroll
        for (int c = 0; c < 4; ++c) {
          uint2v pk;
          pk.x = cvt_pk_bf16(p[c][0], p[c][1]);
          pk.y = cvt_pk_bf16(p[c][2], p[c][3]);
          int byte = (lr * 144 + c * 32 + g * 8) ^ ((lr & 1) << 4);
          *(uint2v*)(psB + byte) = pk;
        }
#pragma unroll
        for (int kb2 = 0; kb2 < 2; ++kb2) {
          int byte = (lr * 144 + kb2 * 64 + g * 16) ^ ((lr & 1) << 4);
          pf[qs][kb2] = *(const short8*)(psB + byte);
        }
      }

      // O += V P : acc_o[qs][dj] holds O[d = dj*16 + g*4 + r][q = lr]
      __builtin_amdgcn_s_setprio(1);
#pragma unroll
      for (int dj = 0; dj < 8; ++dj) {
#pragma unroll
        for (int kb2 = 0; kb2 < 2; ++kb2) {
          int d = dj * 16 + lr;
          int byte = (d * 128 + (kb2 * 32 + g * 8) * 2) ^ ((d & 7) << 4);
          short8 vf = *(const short8*)((char*)Vs + byte);
          acc_o[0][dj] = __builtin_amdgcn_mfma_f32_16x16x32_bf16(vf, pf[0][kb2], acc_o[0][dj], 0, 0, 0);
          acc_o[1][dj] = __builtin_amdgcn_mfma_f32_16x16x32_bf16(vf, pf[1][kb2], acc_o[1][dj], 0, 0, 0);
        }
      }
      __builtin_amdgcn_s_setprio(0);
    }

    // epilogue: O[q][d] = acc_o / l   (4 consecutive d per reg quad -> b64 stores)
#pragma unroll
    for (int qs = 0; qs < 2; ++qs) {
      float rl = 1.0f / lrow[qs];
#pragma unroll
      for (int dj = 0; dj < 8; ++dj) {
        uint2v pk;
        pk.x = cvt_pk_bf16(acc_o[qs][dj][0] * rl, acc_o[qs][dj][1] * rl);
        pk.y = cvt_pk_bf16(acc_o[qs][dj][2] * rl, acc_o[qs][dj][3] * rl);
        *(uint2v*)(&O[(long)(q0 + qs * 16 + lr) * HIDDEN + h * HD + dj * 16 + g * 4]) = pk;
      }
    }
  }
}

// ---------------- launcher ----------------
extern "C" void kernel_launch(void* const* d_in, const int* in_sizes, int n_in,
                              void* d_out, int out_size, void* d_ws, size_t ws_size,
                              hipStream_t stream) {
  const float* hs  = (const float*)d_in[0];
  // d_in[1] = attention_mask (exact causal; applied analytically)
  const int* pos   = (const int*)d_in[2];
  const float* Wq  = (const float*)d_in[3];
  const float* Wk  = (const float*)d_in[4];
  const float* Wv  = (const float*)d_in[5];
  const float* Wo  = (const float*)d_in[6];
  float* out       = (float*)d_out;

  char* ws = (char*)d_ws;
  const long MB = 1024 * 1024;
  bf16_t* hsb   = (bf16_t*)(ws + 0);          // 16MB  [2048][4096]
  bf16_t* wqkvb = (bf16_t*)(ws + 16 * MB);    // 48MB  [6144][4096]: Wq | Wk | Wv rows
  bf16_t* wob   = (bf16_t*)(ws + 64 * MB);    // 32MB  [4096][4096]
  bf16_t* qkvb  = (bf16_t*)(ws + 96 * MB);    // 24MB  [2048][6144]
  bf16_t* vtb   = (bf16_t*)(ws + 120 * MB);   // 4MB   [8][128][2048]
  bf16_t* aob   = (bf16_t*)(ws + 124 * MB);   // 16MB  [2048][4096]
  int*    ctr   = (int*)(ws + 140 * MB);      // 4B task counter

  // 0) reset task counter (re-poisoned to 0xAA before every timed launch)
  hipMemsetAsync(ctr, 0, 4, stream);

  // 1) fp32 -> bf16 (Wq/Wk/Wv stacked into one [6144][4096] weight)
  cvt_f32_bf16<<<(SEQ * HIDDEN) / 1024, 256, 0, stream>>>(hs, hsb);
  cvt_f32_bf16<<<(HIDDEN * HIDDEN) / 1024, 256, 0, stream>>>(Wq, wqkvb);
  cvt_f32_bf16<<<(NKV * HD * HIDDEN) / 1024, 256, 0, stream>>>(Wk, wqkvb + (long)HIDDEN * HIDDEN);
  cvt_f32_bf16<<<(NKV * HD * HIDDEN) / 1024, 256, 0, stream>>>(Wv, wqkvb + (long)(HIDDEN + NKV * HD) * HIDDEN);
  cvt_f32_bf16<<<(HIDDEN * HIDDEN) / 1024, 256, 0, stream>>>(Wo, wob);

  // 2) fused QKV projection: [2048][6144]
  gemm_bt<0><<<dim3(QKVN / 128, SEQ / 128), 256, 0, stream>>>(hsb, wqkvb, qkvb, SEQ, QKVN, HIDDEN);

  // 3) RoPE on Q (cols 0..4095) and K (cols 4096..5119)
  rope_kernel<<<(SEQ * NH * 64) / 256, 256, 0, stream>>>(qkvb, pos, NH, QKVN);
  rope_kernel<<<(SEQ * NKV * 64) / 256, 256, 0, stream>>>(qkvb + HIDDEN, pos, NKV, QKVN);

  // 4) V transpose (V at col offset 5120 in qkvb)
  transpose_v<<<dim3(SEQ / 64, (NKV * HD) / 64), 256, 0, stream>>>(qkvb, vtb, QKVN, HIDDEN + NKV * HD);

  // 5) causal flash attention: 512 persistent blocks, LPT task queue
  attn_kernel<<<NTASK, 256, 0, stream>>>(qkvb, vtb, aob, ctr);

  // 6) output projection (fp32 out)
  gemm_bt<1><<<dim3(HIDDEN / 128, SEQ / 128), 256, 0, stream>>>(aob, wob, out, SEQ, HIDDEN, HIDDEN);
}